// Round 3
// baseline (406.260 us; speedup 1.0000x reference)
//
#include <hip/hip_runtime.h>

typedef short s16x8 __attribute__((ext_vector_type(8)));
typedef float f32x4 __attribute__((ext_vector_type(4)));
typedef unsigned short us;

__device__ inline us f2bf(float f){
    union{float f;unsigned u;} v{f};
    unsigned r = v.u + 0x7fff + ((v.u>>16)&1);
    return (us)(r>>16);
}
__device__ inline float bf2f(us h){
    union{unsigned u;float f;} v{(unsigned)h<<16};
    return v.f;
}

__device__ __forceinline__ void glds16(const us* g, us* l){
    __builtin_amdgcn_global_load_lds(
        (const __attribute__((address_space(1))) unsigned int*)(g),
        (__attribute__((address_space(3))) unsigned int*)(l), 16, 0, 0);
}

// ---------------- cast fp32 -> bf16 (weights only), vectorized x4 ----------------
__global__ void cast_f32_bf16(const float* __restrict__ src, us* __restrict__ dst, int n4){
    int i = blockIdx.x*blockDim.x + threadIdx.x;
    if(i < n4){
        float4 f = ((const float4*)src)[i];
        ushort4 o;
        o.x = f2bf(f.x); o.y = f2bf(f.y); o.z = f2bf(f.z); o.w = f2bf(f.w);
        ((ushort4*)dst)[i] = o;
    }
}

// ---- C[M,N] = A[M,K]*B[N,K]^T + bias, K=512 fixed. A-stripe (64x512) resident in
// LDS (XOR-swizzled 16B chunks), staged ONCE (fused fp32->bf16 cast if CVT).
// K/N loops are BARRIER-FREE: A frags via ds_read_b128 (conflict-free by swizzle),
// B frags direct global->VGPR (B is L2-resident), 1-iter register prefetch.
// 256 thr / 4 waves, wave = 64 rows x 64 cols inside a 256-col N-window.
template<int CVT, int BF16OUT>
__launch_bounds__(256,2)
__global__ void gemm_ares(const void* __restrict__ Av, const us* __restrict__ B,
                          const float* __restrict__ bias, void* __restrict__ Cv,
                          int N){
    __shared__ __attribute__((aligned(16))) us sA[64*512]; // 64 KB
    int t = threadIdx.x;
    int bm = blockIdx.x;
    int lane = t&63, w = t>>6;          // wn = w (0..3)
    int quad = lane>>4, l15 = lane&15;

    // ---- stage A stripe: chunk (r, ck) -> LDS slot r*64 + (ck ^ (r&7)) ----
    if(CVT){
        const float* A = (const float*)Av;
        #pragma unroll
        for(int it=0; it<16; it++){
            int g = it*256 + t;
            int r = g>>6, ck = g&63;
            const float4* gp = (const float4*)(A + ((size_t)(bm*64+r)*512 + ck*8));
            float4 f0 = gp[0], f1 = gp[1];
            ushort4 h0, h1;
            h0.x=f2bf(f0.x); h0.y=f2bf(f0.y); h0.z=f2bf(f0.z); h0.w=f2bf(f0.w);
            h1.x=f2bf(f1.x); h1.y=f2bf(f1.y); h1.z=f2bf(f1.z); h1.w=f2bf(f1.w);
            us* dst = &sA[(size_t)r*512 + (size_t)(ck ^ (r&7))*8];
            *(ushort4*)dst = h0; *(ushort4*)(dst+4) = h1;
        }
    } else {
        const us* A = (const us*)Av;
        #pragma unroll
        for(int it=0; it<16; it++){
            int r0 = it*4 + w;                       // wave-uniform row
            int ck = lane ^ (r0&7);                  // inverse swizzle on global side
            glds16(A + (size_t)(bm*64+r0)*512 + ck*8, &sA[(size_t)r0*512]);
        }
    }
    __syncthreads();   // the ONLY barrier

    for(int nt=0; nt<N; nt+=256){
        int c0 = nt + w*64;
        f32x4 acc[4][4];
        #pragma unroll
        for(int i=0;i<4;i++)
            #pragma unroll
            for(int j=0;j<4;j++) acc[i][j] = (f32x4){0.f,0.f,0.f,0.f};

        s16x8 af[2][4], bf[2][4];
        // prologue: load k=0 fragments
        #pragma unroll
        for(int i=0;i<4;i++){
            int r = i*16 + l15;
            af[0][i] = *(const s16x8*)&sA[(size_t)r*512 + (size_t)((quad ^ (r&7)))*8];
        }
        #pragma unroll
        for(int j=0;j<4;j++)
            bf[0][j] = *(const s16x8*)&B[(size_t)(c0 + j*16 + l15)*512 + quad*8];

        #pragma unroll
        for(int k=0;k<16;k++){
            int cur = k&1, nx = cur^1;
            if(k<15){
                int kc = (k+1)*4 + quad;
                #pragma unroll
                for(int i=0;i<4;i++){
                    int r = i*16 + l15;
                    af[nx][i] = *(const s16x8*)&sA[(size_t)r*512 + (size_t)(kc ^ (r&7))*8];
                }
                #pragma unroll
                for(int j=0;j<4;j++)
                    bf[nx][j] = *(const s16x8*)&B[(size_t)(c0 + j*16 + l15)*512 + (k+1)*32 + quad*8];
            }
            #pragma unroll
            for(int i=0;i<4;i++)
                #pragma unroll
                for(int j=0;j<4;j++)
                    acc[i][j] = __builtin_amdgcn_mfma_f32_16x16x32_bf16(af[cur][i], bf[cur][j], acc[i][j], 0,0,0);
        }

        // epilogue
        #pragma unroll
        for(int j=0;j<4;j++){
            int col = c0 + j*16 + l15;
            float bv = bias[col];
            #pragma unroll
            for(int i=0;i<4;i++){
                int row = bm*64 + i*16 + quad*4;
                #pragma unroll
                for(int r=0;r<4;r++){
                    float v = acc[i][j][r] + bv;
                    if(BF16OUT) ((us*)Cv)[(size_t)(row+r)*N + col] = f2bf(v);
                    else        ((float*)Cv)[(size_t)(row+r)*N + col] = v;
                }
            }
        }
    }
}

// ---- scores via MFMA: Spart[kb][head][d][e] = sum over 512 tokens Q(m,d)K(m,e) ----
__launch_bounds__(256,2)
__global__ void attn_scores_mfma(const us* __restrict__ qkv, float* __restrict__ Sp){
    __shared__ __attribute__((aligned(16))) us sQt[64*64];
    __shared__ __attribute__((aligned(16))) us sKt[64*64];
    int t = threadIdx.x;
    int kb = blockIdx.x, head = blockIdx.y;
    int lane = t & 63, w = t >> 6;
    int quad = lane >> 4, l15 = lane & 15;

    f32x4 acc[4];
    #pragma unroll
    for(int j=0;j<4;j++) acc[j] = (f32x4){0.f,0.f,0.f,0.f};

    for(int chunk=0; chunk<8; chunk++){
        int r0 = head*512 + kb*64 + chunk*8;
        #pragma unroll
        for(int it=0; it<2; it++){
            int i = it*256 + t;
            int row8 = i>>6, l = i&63;
            int d0 = (l&7)*8;
            int off = ((row8 ^ (l&7))<<3) | (l>>3);
            const us* gq = qkv + (size_t)(r0+row8)*1536 + l*8;
            union{uint4 v; us s[8];} q, k;
            q.v = *(const uint4*)gq;
            k.v = *(const uint4*)(gq + 512);
            #pragma unroll
            for(int j=0;j<8;j++){
                sQt[(d0+j)*64 + off] = q.s[j];
                sKt[(d0+j)*64 + off] = k.s[j];
            }
        }
        __syncthreads();
        #pragma unroll
        for(int ks=0; ks<2; ks++){
            int d = w*16 + l15;
            int tb = ks*4 + quad;
            s16x8 af = *(const s16x8*)&sQt[d*64 + ((tb ^ (d>>3))<<3)];
            #pragma unroll
            for(int jt=0; jt<4; jt++){
                int e = jt*16 + l15;
                s16x8 bfv = *(const s16x8*)&sKt[e*64 + ((tb ^ (e>>3))<<3)];
                acc[jt] = __builtin_amdgcn_mfma_f32_16x16x32_bf16(af, bfv, acc[jt], 0,0,0);
            }
        }
        __syncthreads();
    }

    float* S = Sp + (size_t)(kb*64 + head)*4096;
    #pragma unroll
    for(int jt=0; jt<4; jt++){
        int e = jt*16 + l15;
        #pragma unroll
        for(int r=0; r<4; r++){
            int d = w*16 + quad*4 + r;
            S[d*64 + e] = acc[jt][r];
        }
    }
}

// ---- sum 8 partials, softmax over e (scale 1/8), write bf16 weights W[head][d][e] ----
__global__ void softmax_fuse(const float* __restrict__ Sp, us* __restrict__ W){
    int head = blockIdx.x;
    int t = threadIdx.x;           // 256
    int d = t>>2, eg = (t&3)*16;
    float v[16];
    #pragma unroll
    for(int e=0;e<16;e++) v[e]=0.f;
    for(int kb=0; kb<8; kb++){
        const float* p = Sp + (size_t)(kb*64 + head)*4096 + d*64 + eg;
        #pragma unroll
        for(int e4=0;e4<4;e4++){
            float4 f = ((const float4*)p)[e4];
            v[e4*4+0]+=f.x; v[e4*4+1]+=f.y; v[e4*4+2]+=f.z; v[e4*4+3]+=f.w;
        }
    }
    float m = -1e30f;
    #pragma unroll
    for(int e=0;e<16;e++){ v[e] *= 0.125f; m = fmaxf(m, v[e]); }
    m = fmaxf(m, __shfl_xor(m, 1));
    m = fmaxf(m, __shfl_xor(m, 2));
    float s = 0.f;
    #pragma unroll
    for(int e=0;e<16;e++){ v[e] = __expf(v[e]-m); s += v[e]; }
    s += __shfl_xor(s, 1);
    s += __shfl_xor(s, 2);
    float inv = 1.f/s;
    union{uint4 u[2]; us h[16];} o;
    #pragma unroll
    for(int e=0;e<16;e++) o.h[e] = f2bf(v[e]*inv);
    uint4* wp = (uint4*)(W + (size_t)head*4096 + d*64 + eg);
    wp[0] = o.u[0]; wp[1] = o.u[1];
}

// ---------------- attn[b*4096+m, h*64+d] = sum_e V(m,e)*W(d,e), MFMA, K=64 ----------------
__launch_bounds__(256,2)
__global__ void attn_pv(const us* __restrict__ qkv, const us* __restrict__ W,
                        us* __restrict__ attn){
    const int LV = 72;
    __shared__ __attribute__((aligned(16))) us sV[128*72];
    __shared__ __attribute__((aligned(16))) us sW[64*72];
    int t = threadIdx.x;
    int head = blockIdx.y, chunk = blockIdx.x;
    int rbase = head*512;
    #pragma unroll
    for(int it=0; it<4; it++){
        int i = it*2048 + t*8;
        int tok = i>>6, e = i&63;
        int qrow = i>>9, ch = i&511;
        *(uint4*)&sV[tok*LV + e] = *(const uint4*)&qkv[(size_t)(rbase + chunk*16 + qrow)*1536 + 1024 + ch];
    }
    #pragma unroll
    for(int it=0; it<2; it++){
        int i = it*2048 + t*8;
        int dd = i>>6, e = i&63;
        *(uint4*)&sW[dd*LV + e] = *(const uint4*)&W[head*4096 + i];
    }
    __syncthreads();
    int lane = t&63, w = t>>6, quad = lane>>4, l15 = lane&15;
    f32x4 acc[2][4];
    #pragma unroll
    for(int i=0;i<2;i++)
        #pragma unroll
        for(int j=0;j<4;j++) acc[i][j] = (f32x4){0.f,0.f,0.f,0.f};
    #pragma unroll
    for(int ks=0; ks<2; ks++){
        int k0 = ks*32;
        s16x8 af[2], bfr[4];
        #pragma unroll
        for(int mt=0;mt<2;mt++) af[mt]  = *(const s16x8*)&sV[(w*32+mt*16+l15)*LV + k0 + quad*8];
        #pragma unroll
        for(int nt=0;nt<4;nt++) bfr[nt] = *(const s16x8*)&sW[(nt*16+l15)*LV + k0 + quad*8];
        #pragma unroll
        for(int mt=0;mt<2;mt++)
            #pragma unroll
            for(int nt=0;nt<4;nt++)
                acc[mt][nt] = __builtin_amdgcn_mfma_f32_16x16x32_bf16(af[mt], bfr[nt], acc[mt][nt],0,0,0);
    }
    int b = head>>3, h = head&7;
    #pragma unroll
    for(int mt=0;mt<2;mt++){
        int mg = chunk*128 + w*32 + mt*16 + quad*4;
        #pragma unroll
        for(int nt=0;nt<4;nt++){
            int d = nt*16 + l15;
            #pragma unroll
            for(int r=0;r<4;r++){
                attn[(size_t)(b*4096 + mg + r)*512 + h*64 + d] = f2bf(acc[mt][nt][r]);
            }
        }
    }
}

extern "C" void kernel_launch(void* const* d_in, const int* in_sizes, int n_in,
                              void* d_out, int out_size, void* d_ws, size_t ws_size,
                              hipStream_t stream){
    const float* x      = (const float*)d_in[0];
    const float* wqkv_w = (const float*)d_in[1];
    const float* wqkv_b = (const float*)d_in[2];
    const float* wp_w   = (const float*)d_in[3];
    const float* wp_b   = (const float*)d_in[4];

    char* ws = (char*)d_ws;
    us*    qkvbf  = (us*)(ws);                    // 96 MB
    us*    attnbf = (us*)(ws + 100663296);        // 32 MB
    us*    wqkvbf = (us*)(ws + 134217728);        // 1.5 MB
    us*    wpbf   = (us*)(ws + 135790592);        // 0.5 MB
    float* Spart  = (float*)(ws + 136314880);     // 8 MB
    us*    Wsm    = (us*)(ws + 144703488);        // 0.5 MB

    cast_f32_bf16<<<768, 256,0,stream>>>(wqkv_w, wqkvbf, 786432/4);
    cast_f32_bf16<<<256, 256,0,stream>>>(wp_w,   wpbf,   262144/4);

    // qkv = x @ wqkv^T + b  (fused fp32->bf16 read of x; M=32768,N=1536,K=512)
    gemm_ares<1,1><<<512,256,0,stream>>>((const void*)x, wqkvbf, wqkv_b, (void*)qkvbf, 1536);

    // scores: 8-way K-split MFMA partials, then fused sum+softmax
    attn_scores_mfma<<<dim3(8,64),256,0,stream>>>(qkvbf, Spart);
    softmax_fuse<<<64,256,0,stream>>>(Spart, Wsm);

    // y = W @ V^T -> attn (b,n,c) layout, bf16
    attn_pv<<<dim3(32,64),256,0,stream>>>(qkvbf, Wsm, attnbf);

    // out = attn @ wp^T + b  (M=32768,N=512,K=512), fp32 out
    gemm_ares<0,0><<<512,256,0,stream>>>((const void*)attnbf, wpbf, wp_b, d_out, 512);
}

// Round 5
// 275.402 us; speedup vs baseline: 1.4752x; 1.4752x over previous
//
#include <hip/hip_runtime.h>

typedef short s16x8 __attribute__((ext_vector_type(8)));
typedef float f32x4 __attribute__((ext_vector_type(4)));
typedef unsigned short us;

__device__ inline us f2bf(float f){
    union{float f;unsigned u;} v{f};
    unsigned r = v.u + 0x7fff + ((v.u>>16)&1);
    return (us)(r>>16);
}
__device__ inline float bf2f(us h){
    union{unsigned u;float f;} v{(unsigned)h<<16};
    return v.f;
}

__device__ __forceinline__ void glds16(const us* g, us* l){
    __builtin_amdgcn_global_load_lds(
        (const __attribute__((address_space(1))) unsigned int*)(g),
        (__attribute__((address_space(3))) unsigned int*)(l), 16, 0, 0);
}

// ---------------- cast fp32 -> bf16 (weights only) ----------------
__global__ void cast_f32_bf16(const float* __restrict__ src, us* __restrict__ dst, int n4){
    int i = blockIdx.x*blockDim.x + threadIdx.x;
    if(i < n4){
        float4 f = ((const float4*)src)[i];
        ushort4 o;
        o.x = f2bf(f.x); o.y = f2bf(f.y); o.z = f2bf(f.z); o.w = f2bf(f.w);
        ((ushort4*)dst)[i] = o;
    }
}

// ---- qkv = x @ wqkv^T + b : A fp32 (fused cast, register staging), B bf16 via glds.
// 128x128 tile, BK=32, m97 LDS layout [row][32]. XCD swizzle: nt fastest per XCD.
__launch_bounds__(256,2)
__global__ void gemm_qkv(const float* __restrict__ X, const us* __restrict__ B,
                         const float* __restrict__ bias, us* __restrict__ C){
    __shared__ __attribute__((aligned(16))) us sA[128*32];
    __shared__ __attribute__((aligned(16))) us sB[128*32];
    int t = threadIdx.x;
    int id = blockIdx.x;                 // 3072 blocks
    int xcd = id & 7, s = id >> 3;       // 384 slots per XCD
    int nt = s % 12, mt = xcd*32 + s/12; // same-XCD consecutive blocks share A stripe
    int lane = t&63, wave = t>>6, quad = lane>>4, l15 = lane&15;
    int wm = wave>>1, wn = wave&1;

    int srA = t>>1, scA = (t&1)*16;      // thread: 16 fp32 of row srA
    const float* Ag = X + (size_t)(mt*128 + srA)*512 + scA;
    us* sAd = &sA[srA*32 + scA];

    int srB = wave*32 + (lane>>2), scB = (lane&3)*8;
    const us* Bg = B + (size_t)(nt*128 + srB)*512 + scB;
    us* sBw = &sB[(wave*32)*32];

    f32x4 acc[4][4];
    #pragma unroll
    for(int i=0;i<4;i++)
        #pragma unroll
        for(int j=0;j<4;j++) acc[i][j] = (f32x4){0.f,0.f,0.f,0.f};

    float4 p0 = ((const float4*)Ag)[0], p1 = ((const float4*)Ag)[1],
           p2 = ((const float4*)Ag)[2], p3 = ((const float4*)Ag)[3];

    for(int ki=0; ki<16; ki++){
        int k0 = ki*32;
        glds16(Bg + k0,          sBw);
        glds16(Bg + 16*512 + k0, sBw + 16*32);
        union{uint4 u[2]; us h[16];} o;
        o.h[0]=f2bf(p0.x); o.h[1]=f2bf(p0.y); o.h[2]=f2bf(p0.z); o.h[3]=f2bf(p0.w);
        o.h[4]=f2bf(p1.x); o.h[5]=f2bf(p1.y); o.h[6]=f2bf(p1.z); o.h[7]=f2bf(p1.w);
        o.h[8]=f2bf(p2.x); o.h[9]=f2bf(p2.y); o.h[10]=f2bf(p2.z); o.h[11]=f2bf(p2.w);
        o.h[12]=f2bf(p3.x); o.h[13]=f2bf(p3.y); o.h[14]=f2bf(p3.z); o.h[15]=f2bf(p3.w);
        *(uint4*)sAd = o.u[0]; *(uint4*)(sAd+8) = o.u[1];
        if(ki<15){
            const float4* nxt = (const float4*)(Ag + k0 + 32);
            p0 = nxt[0]; p1 = nxt[1]; p2 = nxt[2]; p3 = nxt[3];
        }
        __syncthreads();
        s16x8 af[4], bfr[4];
        #pragma unroll
        for(int i=0;i<4;i++) af[i]  = *(const s16x8*)&sA[(wm*64 + i*16 + l15)*32 + quad*8];
        #pragma unroll
        for(int j=0;j<4;j++) bfr[j] = *(const s16x8*)&sB[(wn*64 + j*16 + l15)*32 + quad*8];
        #pragma unroll
        for(int i=0;i<4;i++)
            #pragma unroll
            for(int j=0;j<4;j++)
                acc[i][j] = __builtin_amdgcn_mfma_f32_16x16x32_bf16(af[i], bfr[j], acc[i][j], 0,0,0);
        __syncthreads();
    }

    int row0 = mt*128 + wm*64, col0 = nt*128 + wn*64;
    #pragma unroll
    for(int j=0;j<4;j++){
        int col = col0 + j*16 + l15;
        float bv = bias[col];
        #pragma unroll
        for(int i=0;i<4;i++){
            int rbase = row0 + i*16 + quad*4;
            #pragma unroll
            for(int r=0;r<4;r++)
                C[(size_t)(rbase+r)*1536 + col] = f2bf(acc[i][j][r] + bv);
        }
    }
}

// ---- scores via MFMA: Spart[kb][head][d][e] = sum over 512 tokens Q(m,d)K(m,e) ----
__launch_bounds__(256,2)
__global__ void attn_scores_mfma(const us* __restrict__ qkv, float* __restrict__ Sp){
    __shared__ __attribute__((aligned(16))) us sQt[64*64];
    __shared__ __attribute__((aligned(16))) us sKt[64*64];
    int t = threadIdx.x;
    int kb = blockIdx.x, head = blockIdx.y;
    int lane = t & 63, w = t >> 6;
    int quad = lane >> 4, l15 = lane & 15;

    f32x4 acc[4];
    #pragma unroll
    for(int j=0;j<4;j++) acc[j] = (f32x4){0.f,0.f,0.f,0.f};

    for(int chunk=0; chunk<8; chunk++){
        int r0 = head*512 + kb*64 + chunk*8;
        #pragma unroll
        for(int it=0; it<2; it++){
            int i = it*256 + t;
            int row8 = i>>6, l = i&63;
            int d0 = (l&7)*8;
            int off = ((row8 ^ (l&7))<<3) | (l>>3);
            const us* gq = qkv + (size_t)(r0+row8)*1536 + l*8;
            union{uint4 v; us s[8];} q, k;
            q.v = *(const uint4*)gq;
            k.v = *(const uint4*)(gq + 512);
            #pragma unroll
            for(int j=0;j<8;j++){
                sQt[(d0+j)*64 + off] = q.s[j];
                sKt[(d0+j)*64 + off] = k.s[j];
            }
        }
        __syncthreads();
        #pragma unroll
        for(int ks=0; ks<2; ks++){
            int d = w*16 + l15;
            int tb = ks*4 + quad;
            s16x8 af = *(const s16x8*)&sQt[d*64 + ((tb ^ (d>>3))<<3)];
            #pragma unroll
            for(int jt=0; jt<4; jt++){
                int e = jt*16 + l15;
                s16x8 bfv = *(const s16x8*)&sKt[e*64 + ((tb ^ (e>>3))<<3)];
                acc[jt] = __builtin_amdgcn_mfma_f32_16x16x32_bf16(af, bfv, acc[jt], 0,0,0);
            }
        }
        __syncthreads();
    }

    float* S = Sp + (size_t)(kb*64 + head)*4096;
    #pragma unroll
    for(int jt=0; jt<4; jt++){
        int e = jt*16 + l15;
        #pragma unroll
        for(int r=0; r<4; r++){
            int d = w*16 + quad*4 + r;
            S[d*64 + e] = acc[jt][r];
        }
    }
}

// ---- sum 8 partials, softmax over e (scale 1/8), write bf16 weights W[head][d][e] ----
__global__ void softmax_fuse(const float* __restrict__ Sp, us* __restrict__ W){
    int head = blockIdx.x;
    int t = threadIdx.x;           // 256
    int d = t>>2, eg = (t&3)*16;
    float v[16];
    #pragma unroll
    for(int e=0;e<16;e++) v[e]=0.f;
    for(int kb=0; kb<8; kb++){
        const float* p = Sp + (size_t)(kb*64 + head)*4096 + d*64 + eg;
        #pragma unroll
        for(int e4=0;e4<4;e4++){
            float4 f = ((const float4*)p)[e4];
            v[e4*4+0]+=f.x; v[e4*4+1]+=f.y; v[e4*4+2]+=f.z; v[e4*4+3]+=f.w;
        }
    }
    float m = -1e30f;
    #pragma unroll
    for(int e=0;e<16;e++){ v[e] *= 0.125f; m = fmaxf(m, v[e]); }
    m = fmaxf(m, __shfl_xor(m, 1));
    m = fmaxf(m, __shfl_xor(m, 2));
    float s = 0.f;
    #pragma unroll
    for(int e=0;e<16;e++){ v[e] = __expf(v[e]-m); s += v[e]; }
    s += __shfl_xor(s, 1);
    s += __shfl_xor(s, 2);
    float inv = 1.f/s;
    union{uint4 u[2]; us h[16];} o;
    #pragma unroll
    for(int e=0;e<16;e++) o.h[e] = f2bf(v[e]*inv);
    uint4* wp = (uint4*)(W + (size_t)head*4096 + d*64 + eg);
    wp[0] = o.u[0]; wp[1] = o.u[1];
}

// ---- M_{b,h}[nO,e] = sum_d wp[nO, h*64+d] * W_{b,h}[d,e]  (512x64x64 per head) ----
__launch_bounds__(256,1)
__global__ void wpfold(const us* __restrict__ wpbf, const us* __restrict__ W,
                       us* __restrict__ Mcat){
    __shared__ us sWt[64*72];   // W^T: sWt[e][d]
    int t = threadIdx.x;
    int head = blockIdx.x, b = head>>3, h = head&7;
    int lane = t&63, w = t>>6, quad = lane>>4, l15 = lane&15;
    #pragma unroll
    for(int it=0; it<2; it++){
        int idx = it*2048 + t*8;
        int d = idx>>6, e0 = idx&63;
        union{uint4 v; us s[8];} q;
        q.v = *(const uint4*)&W[(size_t)head*4096 + idx];
        #pragma unroll
        for(int j=0;j<8;j++) sWt[(e0+j)*72 + d] = q.s[j];
    }
    __syncthreads();
    #pragma unroll
    for(int i=0;i<8;i++){
        int nO = w*128 + i*16 + l15;
        s16x8 af0 = *(const s16x8*)&wpbf[(size_t)nO*512 + h*64 + quad*8];
        s16x8 af1 = *(const s16x8*)&wpbf[(size_t)nO*512 + h*64 + 32 + quad*8];
        #pragma unroll
        for(int j=0;j<4;j++){
            s16x8 bf0 = *(const s16x8*)&sWt[(j*16+l15)*72 + quad*8];
            s16x8 bf1 = *(const s16x8*)&sWt[(j*16+l15)*72 + 32 + quad*8];
            f32x4 acc = (f32x4){0.f,0.f,0.f,0.f};
            acc = __builtin_amdgcn_mfma_f32_16x16x32_bf16(af0, bf0, acc, 0,0,0);
            acc = __builtin_amdgcn_mfma_f32_16x16x32_bf16(af1, bf1, acc, 0,0,0);
            #pragma unroll
            for(int r=0;r<4;r++){
                int row = w*128 + i*16 + quad*4 + r;
                Mcat[((size_t)(b*512 + row))*512 + h*64 + j*16 + l15] = f2bf(acc[r]);
            }
        }
    }
}

// ---- out_b = Vgather_b @ Mcat_b^T + wp_b : V read directly from qkv (gathered glds) ----
__launch_bounds__(256,2)
__global__ void gemm_vout(const us* __restrict__ qkv, const us* __restrict__ Mcat,
                          const float* __restrict__ bias, float* __restrict__ out){
    __shared__ __attribute__((aligned(16))) us sA[128*32];
    __shared__ __attribute__((aligned(16))) us sB[128*32];
    int t = threadIdx.x;
    int id = blockIdx.x;                 // 1024 blocks
    int xcd = id & 7, s = id >> 3;       // 128 slots per XCD
    int nt = s & 3, mt = xcd*32 + (s>>2);
    int b = mt>>5, mr = mt&31;           // batch, m-block within batch
    int lane = t&63, wave = t>>6, quad = lane>>4, l15 = lane&15;
    int wm = wave>>1, wn = wave&1;

    // A (V-gather): tile row r -> token m = mr*128 + r; per-lane global addr
    int r = wave*32 + (lane>>2);
    int m = mr*128 + r;
    const us* Abase = qkv + ((size_t)(8*b)*512 + (m>>3))*1536 + 1024 + (m&7)*64 + (lane&3)*8;
    us* sAw = &sA[(wave*32)*32];

    int srB = wave*32 + (lane>>2), scB = (lane&3)*8;
    const us* Bg = Mcat + ((size_t)(b*512 + nt*128 + srB))*512 + scB;  // FIX: + nt*128
    us* sBw = &sB[(wave*32)*32];

    f32x4 acc[4][4];
    #pragma unroll
    for(int i=0;i<4;i++)
        #pragma unroll
        for(int j=0;j<4;j++) acc[i][j] = (f32x4){0.f,0.f,0.f,0.f};

    for(int ki=0; ki<16; ki++){
        int k0 = ki*32;
        int h = k0>>6, e0 = k0&63;
        const us* Ag = Abase + (size_t)h*512*1536 + e0;
        glds16(Ag,            sAw);
        glds16(Ag + 2*1536,   sAw + 16*32);   // +16 tokens = +2 qkv rows
        glds16(Bg + k0,           sBw);
        glds16(Bg + 16*512 + k0,  sBw + 16*32);
        __syncthreads();
        s16x8 af[4], bfr[4];
        #pragma unroll
        for(int i=0;i<4;i++) af[i]  = *(const s16x8*)&sA[(wm*64 + i*16 + l15)*32 + quad*8];
        #pragma unroll
        for(int j=0;j<4;j++) bfr[j] = *(const s16x8*)&sB[(wn*64 + j*16 + l15)*32 + quad*8];
        #pragma unroll
        for(int i=0;i<4;i++)
            #pragma unroll
            for(int j=0;j<4;j++)
                acc[i][j] = __builtin_amdgcn_mfma_f32_16x16x32_bf16(af[i], bfr[j], acc[i][j], 0,0,0);
        __syncthreads();
    }

    int row0 = b*4096 + mr*128 + wm*64;
    int col0 = nt*128 + wn*64;
    #pragma unroll
    for(int j=0;j<4;j++){
        int col = col0 + j*16 + l15;
        float bv = bias[col];
        #pragma unroll
        for(int i=0;i<4;i++){
            int rbase = row0 + i*16 + quad*4;
            #pragma unroll
            for(int r2=0;r2<4;r2++)
                out[(size_t)(rbase+r2)*512 + col] = acc[i][j][r2] + bv;
        }
    }
}

extern "C" void kernel_launch(void* const* d_in, const int* in_sizes, int n_in,
                              void* d_out, int out_size, void* d_ws, size_t ws_size,
                              hipStream_t stream){
    const float* x      = (const float*)d_in[0];
    const float* wqkv_w = (const float*)d_in[1];
    const float* wqkv_b = (const float*)d_in[2];
    const float* wp_w   = (const float*)d_in[3];
    const float* wp_b   = (const float*)d_in[4];

    char* ws = (char*)d_ws;
    us*    qkvbf  = (us*)(ws);                    // 96 MB
    float* Spart  = (float*)(ws + 100663296);     // 8 MB
    us*    Wsm    = (us*)(ws + 109051904);        // 0.5 MB
    us*    Mcat   = (us*)(ws + 109576192);        // 4 MB
    us*    wqkvbf = (us*)(ws + 113770496);        // 1.5 MB
    us*    wpbf   = (us*)(ws + 115343360);        // 0.5 MB (~110.5 MB total)

    cast_f32_bf16<<<768, 256,0,stream>>>(wqkv_w, wqkvbf, 786432/4);
    cast_f32_bf16<<<256, 256,0,stream>>>(wp_w,   wpbf,   262144/4);

    // qkv = x @ wqkv^T + b (fused fp32 cast; M=32768,N=1536,K=512), XCD-swizzled
    gemm_qkv<<<3072,256,0,stream>>>(x, wqkvbf, wqkv_b, qkvbf);

    // scores: 8-way K-split MFMA partials, then fused sum+softmax
    attn_scores_mfma<<<dim3(8,64),256,0,stream>>>(qkvbf, Spart);
    softmax_fuse<<<64,256,0,stream>>>(Spart, Wsm);

    // fold wp through attention weights: M_{b,h} = wp_h @ W_{b,h}
    wpfold<<<64,256,0,stream>>>(wpbf, Wsm, Mcat);

    // out = Vgather @ Mcat^T + wp_b (fp32 out)
    gemm_vout<<<1024,256,0,stream>>>(qkvbf, Mcat, wp_b, (float*)d_out);
}

// Round 6
// 252.327 us; speedup vs baseline: 1.6100x; 1.0914x over previous
//
#include <hip/hip_runtime.h>

typedef short s16x8 __attribute__((ext_vector_type(8)));
typedef float f32x4 __attribute__((ext_vector_type(4)));
typedef unsigned short us;

__device__ inline us f2bf(float f){
    union{float f;unsigned u;} v{f};
    unsigned r = v.u + 0x7fff + ((v.u>>16)&1);
    return (us)(r>>16);
}

__device__ __forceinline__ void glds16(const us* g, us* l){
    __builtin_amdgcn_global_load_lds(
        (const __attribute__((address_space(1))) unsigned int*)(g),
        (__attribute__((address_space(3))) unsigned int*)(l), 16, 0, 0);
}

// ---------------- cast x fp32 -> bf16 ----------------
__global__ void cast_x(const float* __restrict__ src, us* __restrict__ dst, int n4){
    int i = blockIdx.x*blockDim.x + threadIdx.x;
    if(i < n4){
        float4 f = ((const float4*)src)[i];
        ushort4 o;
        o.x = f2bf(f.x); o.y = f2bf(f.y); o.z = f2bf(f.z); o.w = f2bf(f.w);
        ((ushort4*)dst)[i] = o;
    }
}

// ---------------- cast both weights in one launch ----------------
__global__ void cast_w(const float* __restrict__ wqkv_w, const float* __restrict__ wp_w,
                       us* __restrict__ wqkvbf, us* __restrict__ wpbf){
    int i = blockIdx.x*blockDim.x + threadIdx.x;   // 262144 float4s total
    const float* s; us* d; int j;
    if(i < 196608){ s = wqkv_w; d = wqkvbf; j = i; }
    else          { s = wp_w;   d = wpbf;   j = i - 196608; }
    float4 f = ((const float4*)s)[j];
    ushort4 o;
    o.x = f2bf(f.x); o.y = f2bf(f.y); o.z = f2bf(f.z); o.w = f2bf(f.w);
    ((ushort4*)d)[j] = o;
}

// ---- qkv = xbf @ wqkv^T + b  (M=32768,N=1536,K=512). Round-2 proven m97
// structure (glds16 both operands, [row][32] LDS) + XCD swizzle (nt fastest). ----
__launch_bounds__(256,2)
__global__ void gemm_qkv(const us* __restrict__ A, const us* __restrict__ B,
                         const float* __restrict__ bias, us* __restrict__ C){
    __shared__ __attribute__((aligned(16))) us sA[128*32];
    __shared__ __attribute__((aligned(16))) us sB[128*32];
    int t = threadIdx.x;
    int id = blockIdx.x;                 // 3072
    int xcd = id & 7, s = id >> 3;
    int nt = s % 12, mt = xcd*32 + s/12; // same-XCD neighbors share A stripe
    int lane = t&63, wave = t>>6, quad = lane>>4, l15 = lane&15;
    int wm = wave>>1, wn = wave&1;

    int srow = wave*32 + (lane>>2);
    int scol = (lane&3)*8;
    const us* Ag = A + (size_t)(mt*128 + srow)*512 + scol;
    const us* Bg = B + (size_t)(nt*128 + srow)*512 + scol;
    us* sAw = &sA[(wave*32)*32];
    us* sBw = &sB[(wave*32)*32];

    f32x4 acc[4][4];
    #pragma unroll
    for(int i=0;i<4;i++)
        #pragma unroll
        for(int j=0;j<4;j++) acc[i][j] = (f32x4){0.f,0.f,0.f,0.f};

    for(int k0=0; k0<512; k0+=32){
        glds16(Ag + k0,          sAw);
        glds16(Ag + 16*512 + k0, sAw + 16*32);
        glds16(Bg + k0,          sBw);
        glds16(Bg + 16*512 + k0, sBw + 16*32);
        __syncthreads();
        s16x8 af[4], bfr[4];
        #pragma unroll
        for(int i=0;i<4;i++) af[i]  = *(const s16x8*)&sA[(wm*64 + i*16 + l15)*32 + quad*8];
        #pragma unroll
        for(int j=0;j<4;j++) bfr[j] = *(const s16x8*)&sB[(wn*64 + j*16 + l15)*32 + quad*8];
        #pragma unroll
        for(int i=0;i<4;i++)
            #pragma unroll
            for(int j=0;j<4;j++)
                acc[i][j] = __builtin_amdgcn_mfma_f32_16x16x32_bf16(af[i], bfr[j], acc[i][j], 0,0,0);
        __syncthreads();
    }

    int row0 = mt*128 + wm*64, col0 = nt*128 + wn*64;
    #pragma unroll
    for(int j=0;j<4;j++){
        int col = col0 + j*16 + l15;
        float bv = bias[col];
        #pragma unroll
        for(int i=0;i<4;i++){
            int rbase = row0 + i*16 + quad*4;
            #pragma unroll
            for(int r=0;r<4;r++)
                C[(size_t)(rbase+r)*1536 + col] = f2bf(acc[i][j][r] + bv);
        }
    }
}

// ---- scores: Spart[kb][head][d][e] = sum over 512 tokens Q(m,d)K(m,e) ----
// Transposed staging via dword pair-packing: thread t -> pair p=t&31, d-oct t>>5.
// LDS rows padded to 72 (bank-spread frag reads, 16B-aligned rows).
__launch_bounds__(256,4)
__global__ void attn_scores_mfma(const us* __restrict__ qkv, float* __restrict__ Sp){
    __shared__ __attribute__((aligned(16))) us sQt[64*72];
    __shared__ __attribute__((aligned(16))) us sKt[64*72];
    int t = threadIdx.x;
    int kb = blockIdx.x, head = blockIdx.y;
    int lane = t & 63, w = t >> 6;
    int quad = lane >> 4, l15 = lane & 15;
    int p = t & 31;            // token pair 0..31
    int d0 = (t >> 5) * 8;     // d-oct

    f32x4 acc[4];
    #pragma unroll
    for(int j=0;j<4;j++) acc[j] = (f32x4){0.f,0.f,0.f,0.f};

    for(int chunk=0; chunk<8; chunk++){
        int r0 = head*512 + kb*64 + chunk*8;
        const us* g = qkv + (size_t)(r0 + (p>>2))*1536 + (2*(p&3))*64 + d0;
        union{uint4 v; us h[8];} q0, q1, k0, k1;
        q0.v = *(const uint4*)g;         q1.v = *(const uint4*)(g + 64);
        k0.v = *(const uint4*)(g + 512); k1.v = *(const uint4*)(g + 576);
        #pragma unroll
        for(int j=0;j<8;j++){
            *(unsigned*)&sQt[(d0+j)*72 + 2*p] = (unsigned)q0.h[j] | ((unsigned)q1.h[j]<<16);
            *(unsigned*)&sKt[(d0+j)*72 + 2*p] = (unsigned)k0.h[j] | ((unsigned)k1.h[j]<<16);
        }
        __syncthreads();
        int d = w*16 + l15;
        #pragma unroll
        for(int ks=0; ks<2; ks++){
            int tb = ks*4 + quad;
            s16x8 af = *(const s16x8*)&sQt[d*72 + tb*8];
            #pragma unroll
            for(int jt=0; jt<4; jt++){
                int e = jt*16 + l15;
                s16x8 bfv = *(const s16x8*)&sKt[e*72 + tb*8];
                acc[jt] = __builtin_amdgcn_mfma_f32_16x16x32_bf16(af, bfv, acc[jt], 0,0,0);
            }
        }
        __syncthreads();
    }

    float* S = Sp + (size_t)(kb*64 + head)*4096;
    #pragma unroll
    for(int jt=0; jt<4; jt++){
        int e = jt*16 + l15;
        #pragma unroll
        for(int r=0; r<4; r++){
            int d = w*16 + quad*4 + r;
            S[d*64 + e] = acc[jt][r];
        }
    }
}

// ---- fused: sum 8 partials -> softmax (scale 1/8) -> W in LDS -> M_{b,h} = wp_h @ W ----
__launch_bounds__(256,1)
__global__ void smfold(const float* __restrict__ Sp, const us* __restrict__ wpbf,
                       us* __restrict__ Mcat){
    __shared__ us sWt[64*72];   // W^T: sWt[e][d]
    int t = threadIdx.x;
    int head = blockIdx.x, b = head>>3, h = head&7;
    int lane = t&63, w = t>>6, quad = lane>>4, l15 = lane&15;

    // softmax over e for rows d = t>>2, e-group (t&3)*16
    {
        int d = t>>2, eg = (t&3)*16;
        float v[16];
        #pragma unroll
        for(int e=0;e<16;e++) v[e]=0.f;
        for(int kb=0; kb<8; kb++){
            const float* pp = Sp + (size_t)(kb*64 + head)*4096 + d*64 + eg;
            #pragma unroll
            for(int e4=0;e4<4;e4++){
                float4 f = ((const float4*)pp)[e4];
                v[e4*4+0]+=f.x; v[e4*4+1]+=f.y; v[e4*4+2]+=f.z; v[e4*4+3]+=f.w;
            }
        }
        float m = -1e30f;
        #pragma unroll
        for(int e=0;e<16;e++){ v[e] *= 0.125f; m = fmaxf(m, v[e]); }
        m = fmaxf(m, __shfl_xor(m, 1));
        m = fmaxf(m, __shfl_xor(m, 2));
        float s = 0.f;
        #pragma unroll
        for(int e=0;e<16;e++){ v[e] = __expf(v[e]-m); s += v[e]; }
        s += __shfl_xor(s, 1);
        s += __shfl_xor(s, 2);
        float inv = 1.f/s;
        #pragma unroll
        for(int e=0;e<16;e++) sWt[(eg+e)*72 + d] = f2bf(v[e]*inv);
    }
    __syncthreads();

    // fold: M[nO][e] = sum_d wp[nO][h*64+d] * W[d][e]
    #pragma unroll
    for(int i=0;i<8;i++){
        int nO = w*128 + i*16 + l15;
        s16x8 af0 = *(const s16x8*)&wpbf[(size_t)nO*512 + h*64 + quad*8];
        s16x8 af1 = *(const s16x8*)&wpbf[(size_t)nO*512 + h*64 + 32 + quad*8];
        #pragma unroll
        for(int j=0;j<4;j++){
            s16x8 bf0 = *(const s16x8*)&sWt[(j*16+l15)*72 + quad*8];
            s16x8 bf1 = *(const s16x8*)&sWt[(j*16+l15)*72 + 32 + quad*8];
            f32x4 acc = (f32x4){0.f,0.f,0.f,0.f};
            acc = __builtin_amdgcn_mfma_f32_16x16x32_bf16(af0, bf0, acc, 0,0,0);
            acc = __builtin_amdgcn_mfma_f32_16x16x32_bf16(af1, bf1, acc, 0,0,0);
            #pragma unroll
            for(int r=0;r<4;r++){
                int row = w*128 + i*16 + quad*4 + r;
                Mcat[((size_t)(b*512 + row))*512 + h*64 + j*16 + l15] = f2bf(acc[r]);
            }
        }
    }
}

// ---- out_b = Vgather_b @ Mcat_b^T + wp_b : V read directly from qkv (gathered glds) ----
__launch_bounds__(256,2)
__global__ void gemm_vout(const us* __restrict__ qkv, const us* __restrict__ Mcat,
                          const float* __restrict__ bias, float* __restrict__ out){
    __shared__ __attribute__((aligned(16))) us sA[128*32];
    __shared__ __attribute__((aligned(16))) us sB[128*32];
    int t = threadIdx.x;
    int id = blockIdx.x;                 // 1024
    int xcd = id & 7, s = id >> 3;
    int nt = s & 3, mt = xcd*32 + (s>>2);
    int b = mt>>5, mr = mt&31;
    int lane = t&63, wave = t>>6, quad = lane>>4, l15 = lane&15;
    int wm = wave>>1, wn = wave&1;

    int r = wave*32 + (lane>>2);
    int m = mr*128 + r;
    const us* Abase = qkv + ((size_t)(8*b)*512 + (m>>3))*1536 + 1024 + (m&7)*64 + (lane&3)*8;
    us* sAw = &sA[(wave*32)*32];

    int srB = wave*32 + (lane>>2), scB = (lane&3)*8;
    const us* Bg = Mcat + ((size_t)(b*512 + nt*128 + srB))*512 + scB;
    us* sBw = &sB[(wave*32)*32];

    f32x4 acc[4][4];
    #pragma unroll
    for(int i=0;i<4;i++)
        #pragma unroll
        for(int j=0;j<4;j++) acc[i][j] = (f32x4){0.f,0.f,0.f,0.f};

    for(int ki=0; ki<16; ki++){
        int k0 = ki*32;
        int h = k0>>6, e0 = k0&63;
        const us* Ag = Abase + (size_t)h*512*1536 + e0;
        glds16(Ag,            sAw);
        glds16(Ag + 2*1536,   sAw + 16*32);
        glds16(Bg + k0,           sBw);
        glds16(Bg + 16*512 + k0,  sBw + 16*32);
        __syncthreads();
        s16x8 af[4], bfr[4];
        #pragma unroll
        for(int i=0;i<4;i++) af[i]  = *(const s16x8*)&sA[(wm*64 + i*16 + l15)*32 + quad*8];
        #pragma unroll
        for(int j=0;j<4;j++) bfr[j] = *(const s16x8*)&sB[(wn*64 + j*16 + l15)*32 + quad*8];
        #pragma unroll
        for(int i=0;i<4;i++)
            #pragma unroll
            for(int j=0;j<4;j++)
                acc[i][j] = __builtin_amdgcn_mfma_f32_16x16x32_bf16(af[i], bfr[j], acc[i][j], 0,0,0);
        __syncthreads();
    }

    int row0 = b*4096 + mr*128 + wm*64;
    int col0 = nt*128 + wn*64;
    #pragma unroll
    for(int j=0;j<4;j++){
        int col = col0 + j*16 + l15;
        float bv = bias[col];
        #pragma unroll
        for(int i=0;i<4;i++){
            int rbase = row0 + i*16 + quad*4;
            #pragma unroll
            for(int r2=0;r2<4;r2++)
                out[(size_t)(rbase+r2)*512 + col] = acc[i][j][r2] + bv;
        }
    }
}

extern "C" void kernel_launch(void* const* d_in, const int* in_sizes, int n_in,
                              void* d_out, int out_size, void* d_ws, size_t ws_size,
                              hipStream_t stream){
    const float* x      = (const float*)d_in[0];
    const float* wqkv_w = (const float*)d_in[1];
    const float* wqkv_b = (const float*)d_in[2];
    const float* wp_w   = (const float*)d_in[3];
    const float* wp_b   = (const float*)d_in[4];

    char* ws = (char*)d_ws;
    us*    qkvbf  = (us*)(ws);                    // 96 MB
    us*    xbf    = (us*)(ws + 100663296);        // 32 MB
    float* Spart  = (float*)(ws + 134217728);     // 8 MB
    us*    Mcat   = (us*)(ws + 142606336);        // 4 MB
    us*    wqkvbf = (us*)(ws + 146800640);        // 1.5 MB
    us*    wpbf   = (us*)(ws + 148373504);        // 0.5 MB (~142 MB total)

    cast_w<<<1024,256,0,stream>>>(wqkv_w, wp_w, wqkvbf, wpbf);
    cast_x<<<16384,256,0,stream>>>(x, xbf, 16777216/4);

    // qkv = xbf @ wqkv^T + b (glds16 structure + XCD swizzle)
    gemm_qkv<<<3072,256,0,stream>>>(xbf, wqkvbf, wqkv_b, qkvbf);

    // scores: 8-way K-split MFMA partials
    attn_scores_mfma<<<dim3(8,64),256,0,stream>>>(qkvbf, Spart);

    // fused softmax + wp-fold: M_{b,h} = wp_h @ softmax(S_{b,h})
    smfold<<<64,256,0,stream>>>(Spart, wpbf, Mcat);

    // out = Vgather @ Mcat^T + wp_b (fp32 out)
    gemm_vout<<<1024,256,0,stream>>>(qkvbf, Mcat, wp_b, (float*)d_out);
}

// Round 7
// 234.441 us; speedup vs baseline: 1.7329x; 1.0763x over previous
//
#include <hip/hip_runtime.h>

typedef short s16x8 __attribute__((ext_vector_type(8)));
typedef float f32x4 __attribute__((ext_vector_type(4)));
typedef unsigned short us;

__device__ inline us f2bf(float f){
    union{float f;unsigned u;} v{f};
    unsigned r = v.u + 0x7fff + ((v.u>>16)&1);
    return (us)(r>>16);
}

__device__ __forceinline__ void glds16(const us* g, us* l){
    __builtin_amdgcn_global_load_lds(
        (const __attribute__((address_space(1))) unsigned int*)(g),
        (__attribute__((address_space(3))) unsigned int*)(l), 16, 0, 0);
}

// ---------------- cast x fp32 -> bf16 ----------------
__global__ void cast_x(const float* __restrict__ src, us* __restrict__ dst, int n4){
    int i = blockIdx.x*blockDim.x + threadIdx.x;
    if(i < n4){
        float4 f = ((const float4*)src)[i];
        ushort4 o;
        o.x = f2bf(f.x); o.y = f2bf(f.y); o.z = f2bf(f.z); o.w = f2bf(f.w);
        ((ushort4*)dst)[i] = o;
    }
}

// ---------------- cast both weights in one launch ----------------
__global__ void cast_w(const float* __restrict__ wqkv_w, const float* __restrict__ wp_w,
                       us* __restrict__ wqkvbf, us* __restrict__ wpbf){
    int i = blockIdx.x*blockDim.x + threadIdx.x;
    const float* s; us* d; int j;
    if(i < 196608){ s = wqkv_w; d = wqkvbf; j = i; }
    else          { s = wp_w;   d = wpbf;   j = i - 196608; }
    float4 f = ((const float4*)s)[j];
    ushort4 o;
    o.x = f2bf(f.x); o.y = f2bf(f.y); o.z = f2bf(f.z); o.w = f2bf(f.w);
    ((ushort4*)d)[j] = o;
}

// ---- qkv = xbf @ wqkv^T + b  (M=32768,N=1536,K=512). BK=64, XOR-swizzled LDS
// ([row][64], chunk ^= row&7 -> conflict-free b128 frag reads), glds16 staging,
// XCD swizzle (nt fastest). 8 K-iters, 32 MFMA per barrier pair. ----
__launch_bounds__(256,2)
__global__ void gemm_qkv(const us* __restrict__ A, const us* __restrict__ B,
                         const float* __restrict__ bias, us* __restrict__ C){
    __shared__ __attribute__((aligned(16))) us sA[128*64];
    __shared__ __attribute__((aligned(16))) us sB[128*64];
    int t = threadIdx.x;
    int id = blockIdx.x;                 // 3072
    int xcd = id & 7, s = id >> 3;
    int nt = s % 12, mt = xcd*32 + s/12;
    int lane = t&63, wave = t>>6, quad = lane>>4, l15 = lane&15;
    int wm = wave>>1, wn = wave&1;

    int l8 = lane>>3;                    // row-in-call 0..7
    int sw = ((lane&7) ^ l8)*8;          // swizzled 16B-chunk col
    const us* Ag = A + (size_t)(mt*128 + wave*32 + l8)*512 + sw;
    const us* Bg = B + (size_t)(nt*128 + wave*32 + l8)*512 + sw;
    us* sAw = &sA[(wave*32)*64];
    us* sBw = &sB[(wave*32)*64];

    f32x4 acc[4][4];
    #pragma unroll
    for(int i=0;i<4;i++)
        #pragma unroll
        for(int j=0;j<4;j++) acc[i][j] = (f32x4){0.f,0.f,0.f,0.f};

    for(int k0=0; k0<512; k0+=64){
        glds16(Ag + k0,           sAw);
        glds16(Ag + 8*512 + k0,   sAw + 8*64);
        glds16(Ag + 16*512 + k0,  sAw + 16*64);
        glds16(Ag + 24*512 + k0,  sAw + 24*64);
        glds16(Bg + k0,           sBw);
        glds16(Bg + 8*512 + k0,   sBw + 8*64);
        glds16(Bg + 16*512 + k0,  sBw + 16*64);
        glds16(Bg + 24*512 + k0,  sBw + 24*64);
        __syncthreads();
        #pragma unroll
        for(int ks=0; ks<2; ks++){
            int kc = ks*4 + quad;
            s16x8 af[4], bfr[4];
            #pragma unroll
            for(int i=0;i<4;i++){
                int r = wm*64 + i*16 + l15;
                af[i] = *(const s16x8*)&sA[r*64 + ((kc ^ (r&7))<<3)];
            }
            #pragma unroll
            for(int j=0;j<4;j++){
                int r = wn*64 + j*16 + l15;
                bfr[j] = *(const s16x8*)&sB[r*64 + ((kc ^ (r&7))<<3)];
            }
            #pragma unroll
            for(int i=0;i<4;i++)
                #pragma unroll
                for(int j=0;j<4;j++)
                    acc[i][j] = __builtin_amdgcn_mfma_f32_16x16x32_bf16(af[i], bfr[j], acc[i][j], 0,0,0);
        }
        __syncthreads();
    }

    int row0 = mt*128 + wm*64, col0 = nt*128 + wn*64;
    #pragma unroll
    for(int j=0;j<4;j++){
        int col = col0 + j*16 + l15;
        float bv = bias[col];
        #pragma unroll
        for(int i=0;i<4;i++){
            int rbase = row0 + i*16 + quad*4;
            #pragma unroll
            for(int r=0;r<4;r++)
                C[(size_t)(rbase+r)*1536 + col] = f2bf(acc[i][j][r] + bv);
        }
    }
}

// ---- scores: Spart[kb][head][d][e] = partial sum over 256 tokens Q(m,d)K(m,e) ----
__launch_bounds__(256,4)
__global__ void attn_scores_mfma(const us* __restrict__ qkv, float* __restrict__ Sp){
    __shared__ __attribute__((aligned(16))) us sQt[64*72];
    __shared__ __attribute__((aligned(16))) us sKt[64*72];
    int t = threadIdx.x;
    int kb = blockIdx.x, head = blockIdx.y;   // kb < 16
    int lane = t & 63, w = t >> 6;
    int quad = lane >> 4, l15 = lane & 15;
    int p = t & 31;
    int d0 = (t >> 5) * 8;

    f32x4 acc[4];
    #pragma unroll
    for(int j=0;j<4;j++) acc[j] = (f32x4){0.f,0.f,0.f,0.f};

    for(int chunk=0; chunk<4; chunk++){
        int r0 = head*512 + kb*32 + chunk*8;
        const us* g = qkv + (size_t)(r0 + (p>>2))*1536 + (2*(p&3))*64 + d0;
        union{uint4 v; us h[8];} q0, q1, k0, k1;
        q0.v = *(const uint4*)g;         q1.v = *(const uint4*)(g + 64);
        k0.v = *(const uint4*)(g + 512); k1.v = *(const uint4*)(g + 576);
        #pragma unroll
        for(int j=0;j<8;j++){
            *(unsigned*)&sQt[(d0+j)*72 + 2*p] = (unsigned)q0.h[j] | ((unsigned)q1.h[j]<<16);
            *(unsigned*)&sKt[(d0+j)*72 + 2*p] = (unsigned)k0.h[j] | ((unsigned)k1.h[j]<<16);
        }
        __syncthreads();
        int d = w*16 + l15;
        #pragma unroll
        for(int ks=0; ks<2; ks++){
            int tb = ks*4 + quad;
            s16x8 af = *(const s16x8*)&sQt[d*72 + tb*8];
            #pragma unroll
            for(int jt=0; jt<4; jt++){
                int e = jt*16 + l15;
                s16x8 bfv = *(const s16x8*)&sKt[e*72 + tb*8];
                acc[jt] = __builtin_amdgcn_mfma_f32_16x16x32_bf16(af, bfv, acc[jt], 0,0,0);
            }
        }
        __syncthreads();
    }

    float* S = Sp + (size_t)(kb*64 + head)*4096;
    #pragma unroll
    for(int jt=0; jt<4; jt++){
        int e = jt*16 + l15;
        #pragma unroll
        for(int r=0; r<4; r++){
            int d = w*16 + quad*4 + r;
            S[d*64 + e] = acc[jt][r];
        }
    }
}

// ---- sum 16 partials, softmax over e (scale 1/8), write bf16 W[head][d][e] ----
__global__ void softmax64(const float* __restrict__ Sp, us* __restrict__ W){
    int head = blockIdx.x;
    int t = threadIdx.x;           // 256
    int d = t>>2, eg = (t&3)*16;
    float v[16];
    #pragma unroll
    for(int e=0;e<16;e++) v[e]=0.f;
    for(int kb=0; kb<16; kb++){
        const float* pp = Sp + (size_t)(kb*64 + head)*4096 + d*64 + eg;
        #pragma unroll
        for(int e4=0;e4<4;e4++){
            float4 f = ((const float4*)pp)[e4];
            v[e4*4+0]+=f.x; v[e4*4+1]+=f.y; v[e4*4+2]+=f.z; v[e4*4+3]+=f.w;
        }
    }
    float m = -1e30f;
    #pragma unroll
    for(int e=0;e<16;e++){ v[e] *= 0.125f; m = fmaxf(m, v[e]); }
    m = fmaxf(m, __shfl_xor(m, 1));
    m = fmaxf(m, __shfl_xor(m, 2));
    float s = 0.f;
    #pragma unroll
    for(int e=0;e<16;e++){ v[e] = __expf(v[e]-m); s += v[e]; }
    s += __shfl_xor(s, 1);
    s += __shfl_xor(s, 2);
    float inv = 1.f/s;
    union{uint4 u[2]; us h[16];} o;
    #pragma unroll
    for(int e=0;e<16;e++) o.h[e] = f2bf(v[e]*inv);
    uint4* wp = (uint4*)(W + (size_t)head*4096 + d*64 + eg);
    wp[0] = o.u[0]; wp[1] = o.u[1];
}

// ---- M_{b,h}[nO,e] = sum_d wp[nO,h*64+d]*W[d,e]; 256 blocks (4 per head) ----
__launch_bounds__(256,2)
__global__ void fold(const us* __restrict__ Wsm, const us* __restrict__ wpbf,
                     us* __restrict__ Mcat){
    __shared__ us sWt[64*72];   // W^T: sWt[e][d]
    int t = threadIdx.x;
    int head = blockIdx.x>>2, part = blockIdx.x&3;
    int b = head>>3, h = head&7;
    int lane = t&63, w = t>>6, quad = lane>>4, l15 = lane&15;
    #pragma unroll
    for(int it=0; it<2; it++){
        int idx = it*2048 + t*8;
        int d = idx>>6, e0 = idx&63;
        union{uint4 v; us s[8];} q;
        q.v = *(const uint4*)&Wsm[(size_t)head*4096 + idx];
        #pragma unroll
        for(int j=0;j<8;j++) sWt[(e0+j)*72 + d] = q.s[j];
    }
    __syncthreads();
    #pragma unroll
    for(int i=0;i<2;i++){
        int nO = part*128 + w*32 + i*16 + l15;
        s16x8 af0 = *(const s16x8*)&wpbf[(size_t)nO*512 + h*64 + quad*8];
        s16x8 af1 = *(const s16x8*)&wpbf[(size_t)nO*512 + h*64 + 32 + quad*8];
        #pragma unroll
        for(int j=0;j<4;j++){
            s16x8 bf0 = *(const s16x8*)&sWt[(j*16+l15)*72 + quad*8];
            s16x8 bf1 = *(const s16x8*)&sWt[(j*16+l15)*72 + 32 + quad*8];
            f32x4 acc = (f32x4){0.f,0.f,0.f,0.f};
            acc = __builtin_amdgcn_mfma_f32_16x16x32_bf16(af0, bf0, acc, 0,0,0);
            acc = __builtin_amdgcn_mfma_f32_16x16x32_bf16(af1, bf1, acc, 0,0,0);
            #pragma unroll
            for(int r=0;r<4;r++){
                int row = part*128 + w*32 + i*16 + quad*4 + r;
                Mcat[((size_t)(b*512 + row))*512 + h*64 + j*16 + l15] = f2bf(acc[r]);
            }
        }
    }
}

// ---- out_b = Vgather_b @ Mcat_b^T + wp_b. BK=64 (one head per iter), swizzled. ----
__launch_bounds__(256,2)
__global__ void gemm_vout(const us* __restrict__ qkv, const us* __restrict__ Mcat,
                          const float* __restrict__ bias, float* __restrict__ out){
    __shared__ __attribute__((aligned(16))) us sA[128*64];
    __shared__ __attribute__((aligned(16))) us sB[128*64];
    int t = threadIdx.x;
    int id = blockIdx.x;                 // 1024
    int xcd = id & 7, s = id >> 3;
    int nt = s & 3, mt = xcd*32 + (s>>2);
    int b = mt>>5, mr = mt&31;
    int lane = t&63, wave = t>>6, quad = lane>>4, l15 = lane&15;
    int wm = wave>>1, wn = wave&1;

    int l8 = lane>>3;
    int sw = ((lane&7) ^ l8)*8;
    // A: V for head h, call c: qkv row (8b+h)*512 + mr*16 + wave*4 + c,
    //    col 1024 + l8*64 + sw   (token m = mr*128+wave*32+c*8+l8)
    const us* Abase = qkv + ((size_t)(8*b)*512 + mr*16 + wave*4)*1536 + 1024 + l8*64 + sw;
    // B: Mcat row b*512 + nt*128 + wave*32 + c*8 + l8, col h*64 + sw
    const us* Bbase = Mcat + ((size_t)(b*512 + nt*128 + wave*32 + l8))*512 + sw;
    us* sAw = &sA[(wave*32)*64];
    us* sBw = &sB[(wave*32)*64];

    f32x4 acc[4][4];
    #pragma unroll
    for(int i=0;i<4;i++)
        #pragma unroll
        for(int j=0;j<4;j++) acc[i][j] = (f32x4){0.f,0.f,0.f,0.f};

    for(int h=0; h<8; h++){
        const us* Ah = Abase + (size_t)h*512*1536;
        const us* Bh = Bbase + h*64;
        glds16(Ah,           sAw);
        glds16(Ah + 1536,    sAw + 8*64);
        glds16(Ah + 2*1536,  sAw + 16*64);
        glds16(Ah + 3*1536,  sAw + 24*64);
        glds16(Bh,           sBw);
        glds16(Bh + 8*512,   sBw + 8*64);
        glds16(Bh + 16*512,  sBw + 16*64);
        glds16(Bh + 24*512,  sBw + 24*64);
        __syncthreads();
        #pragma unroll
        for(int ks=0; ks<2; ks++){
            int kc = ks*4 + quad;
            s16x8 af[4], bfr[4];
            #pragma unroll
            for(int i=0;i<4;i++){
                int r = wm*64 + i*16 + l15;
                af[i] = *(const s16x8*)&sA[r*64 + ((kc ^ (r&7))<<3)];
            }
            #pragma unroll
            for(int j=0;j<4;j++){
                int r = wn*64 + j*16 + l15;
                bfr[j] = *(const s16x8*)&sB[r*64 + ((kc ^ (r&7))<<3)];
            }
            #pragma unroll
            for(int i=0;i<4;i++)
                #pragma unroll
                for(int j=0;j<4;j++)
                    acc[i][j] = __builtin_amdgcn_mfma_f32_16x16x32_bf16(af[i], bfr[j], acc[i][j], 0,0,0);
        }
        __syncthreads();
    }

    int row0 = b*4096 + mr*128 + wm*64;
    int col0 = nt*128 + wn*64;
    #pragma unroll
    for(int j=0;j<4;j++){
        int col = col0 + j*16 + l15;
        float bv = bias[col];
        #pragma unroll
        for(int i=0;i<4;i++){
            int rbase = row0 + i*16 + quad*4;
            #pragma unroll
            for(int r2=0;r2<4;r2++)
                out[(size_t)(rbase+r2)*512 + col] = acc[i][j][r2] + bv;
        }
    }
}

extern "C" void kernel_launch(void* const* d_in, const int* in_sizes, int n_in,
                              void* d_out, int out_size, void* d_ws, size_t ws_size,
                              hipStream_t stream){
    const float* x      = (const float*)d_in[0];
    const float* wqkv_w = (const float*)d_in[1];
    const float* wqkv_b = (const float*)d_in[2];
    const float* wp_w   = (const float*)d_in[3];
    const float* wp_b   = (const float*)d_in[4];

    char* ws = (char*)d_ws;
    us*    qkvbf  = (us*)(ws);                    // 96 MB
    us*    xbf    = (us*)(ws + 100663296);        // 32 MB
    float* Spart  = (float*)(ws + 134217728);     // 16 MB
    us*    Wsm    = (us*)(ws + 150994944);        // 0.5 MB
    us*    Mcat   = (us*)(ws + 151519232);        // 4 MB
    us*    wqkvbf = (us*)(ws + 155713536);        // 1.5 MB
    us*    wpbf   = (us*)(ws + 157286400);        // 0.5 MB (~150.5 MB)

    cast_w<<<1024,256,0,stream>>>(wqkv_w, wp_w, wqkvbf, wpbf);
    cast_x<<<16384,256,0,stream>>>(x, xbf, 16777216/4);

    gemm_qkv<<<3072,256,0,stream>>>(xbf, wqkvbf, wqkv_b, qkvbf);

    attn_scores_mfma<<<dim3(16,64),256,0,stream>>>(qkvbf, Spart);
    softmax64<<<64,256,0,stream>>>(Spart, Wsm);
    fold<<<256,256,0,stream>>>(Wsm, wpbf, Mcat);

    gemm_vout<<<1024,256,0,stream>>>(qkvbf, Mcat, wp_b, (float*)d_out);
}

// Round 8
// 232.559 us; speedup vs baseline: 1.7469x; 1.0081x over previous
//
#include <hip/hip_runtime.h>

typedef short s16x8 __attribute__((ext_vector_type(8)));
typedef float f32x4 __attribute__((ext_vector_type(4)));
typedef unsigned short us;

__device__ inline us f2bf(float f){
    union{float f;unsigned u;} v{f};
    unsigned r = v.u + 0x7fff + ((v.u>>16)&1);
    return (us)(r>>16);
}

__device__ __forceinline__ void glds16(const us* g, us* l){
    __builtin_amdgcn_global_load_lds(
        (const __attribute__((address_space(1))) unsigned int*)(g),
        (__attribute__((address_space(3))) unsigned int*)(l), 16, 0, 0);
}

// ---------------- fused cast: x, wqkv_w, wp_w -> bf16, one launch ----------------
__global__ void cast_all(const float* __restrict__ x, const float* __restrict__ wqkv_w,
                         const float* __restrict__ wp_w, us* __restrict__ xbf,
                         us* __restrict__ wqkvbf, us* __restrict__ wpbf){
    int i = blockIdx.x*blockDim.x + threadIdx.x;   // 4456448 float4s
    const float* s; us* d; int j;
    if(i < 4194304){ s = x; d = xbf; j = i; }
    else if(i < 4390912){ s = wqkv_w; d = wqkvbf; j = i - 4194304; }
    else { s = wp_w; d = wpbf; j = i - 4390912; }
    float4 f = ((const float4*)s)[j];
    ushort4 o;
    o.x = f2bf(f.x); o.y = f2bf(f.y); o.z = f2bf(f.z); o.w = f2bf(f.w);
    ((ushort4*)d)[j] = o;
}

// ---- qkv = xbf @ wqkv^T + b  (M=32768,N=1536,K=512). BK=64, XOR-swizzled LDS,
// glds16 staging, XCD swizzle. launch_bounds raised to probe occupancy. ----
__launch_bounds__(256,4)
__global__ void gemm_qkv(const us* __restrict__ A, const us* __restrict__ B,
                         const float* __restrict__ bias, us* __restrict__ C){
    __shared__ __attribute__((aligned(16))) us sA[128*64];
    __shared__ __attribute__((aligned(16))) us sB[128*64];
    int t = threadIdx.x;
    int id = blockIdx.x;                 // 3072
    int xcd = id & 7, s = id >> 3;
    int nt = s % 12, mt = xcd*32 + s/12;
    int lane = t&63, wave = t>>6, quad = lane>>4, l15 = lane&15;
    int wm = wave>>1, wn = wave&1;

    int l8 = lane>>3;
    int sw = ((lane&7) ^ l8)*8;
    const us* Ag = A + (size_t)(mt*128 + wave*32 + l8)*512 + sw;
    const us* Bg = B + (size_t)(nt*128 + wave*32 + l8)*512 + sw;
    us* sAw = &sA[(wave*32)*64];
    us* sBw = &sB[(wave*32)*64];

    f32x4 acc[4][4];
    #pragma unroll
    for(int i=0;i<4;i++)
        #pragma unroll
        for(int j=0;j<4;j++) acc[i][j] = (f32x4){0.f,0.f,0.f,0.f};

    for(int k0=0; k0<512; k0+=64){
        glds16(Ag + k0,           sAw);
        glds16(Ag + 8*512 + k0,   sAw + 8*64);
        glds16(Ag + 16*512 + k0,  sAw + 16*64);
        glds16(Ag + 24*512 + k0,  sAw + 24*64);
        glds16(Bg + k0,           sBw);
        glds16(Bg + 8*512 + k0,   sBw + 8*64);
        glds16(Bg + 16*512 + k0,  sBw + 16*64);
        glds16(Bg + 24*512 + k0,  sBw + 24*64);
        __syncthreads();
        #pragma unroll
        for(int ks=0; ks<2; ks++){
            int kc = ks*4 + quad;
            s16x8 af[4], bfr[4];
            #pragma unroll
            for(int i=0;i<4;i++){
                int r = wm*64 + i*16 + l15;
                af[i] = *(const s16x8*)&sA[r*64 + ((kc ^ (r&7))<<3)];
            }
            #pragma unroll
            for(int j=0;j<4;j++){
                int r = wn*64 + j*16 + l15;
                bfr[j] = *(const s16x8*)&sB[r*64 + ((kc ^ (r&7))<<3)];
            }
            #pragma unroll
            for(int i=0;i<4;i++)
                #pragma unroll
                for(int j=0;j<4;j++)
                    acc[i][j] = __builtin_amdgcn_mfma_f32_16x16x32_bf16(af[i], bfr[j], acc[i][j], 0,0,0);
        }
        __syncthreads();
    }

    int row0 = mt*128 + wm*64, col0 = nt*128 + wn*64;
    #pragma unroll
    for(int j=0;j<4;j++){
        int col = col0 + j*16 + l15;
        float bv = bias[col];
        #pragma unroll
        for(int i=0;i<4;i++){
            int rbase = row0 + i*16 + quad*4;
            #pragma unroll
            for(int r=0;r<4;r++)
                C[(size_t)(rbase+r)*1536 + col] = f2bf(acc[i][j][r] + bv);
        }
    }
}

// ---- scores: Spart[kb][head][d][e] = partial over 512 tokens (kb<8, 8 chunks) ----
__launch_bounds__(256,4)
__global__ void attn_scores_mfma(const us* __restrict__ qkv, float* __restrict__ Sp){
    __shared__ __attribute__((aligned(16))) us sQt[64*72];
    __shared__ __attribute__((aligned(16))) us sKt[64*72];
    int t = threadIdx.x;
    int kb = blockIdx.x, head = blockIdx.y;   // kb < 8
    int lane = t & 63, w = t >> 6;
    int quad = lane >> 4, l15 = lane & 15;
    int p = t & 31;
    int d0 = (t >> 5) * 8;

    f32x4 acc[4];
    #pragma unroll
    for(int j=0;j<4;j++) acc[j] = (f32x4){0.f,0.f,0.f,0.f};

    for(int chunk=0; chunk<8; chunk++){
        int r0 = head*512 + kb*64 + chunk*8;
        const us* g = qkv + (size_t)(r0 + (p>>2))*1536 + (2*(p&3))*64 + d0;
        union{uint4 v; us h[8];} q0, q1, k0, k1;
        q0.v = *(const uint4*)g;         q1.v = *(const uint4*)(g + 64);
        k0.v = *(const uint4*)(g + 512); k1.v = *(const uint4*)(g + 576);
        #pragma unroll
        for(int j=0;j<8;j++){
            *(unsigned*)&sQt[(d0+j)*72 + 2*p] = (unsigned)q0.h[j] | ((unsigned)q1.h[j]<<16);
            *(unsigned*)&sKt[(d0+j)*72 + 2*p] = (unsigned)k0.h[j] | ((unsigned)k1.h[j]<<16);
        }
        __syncthreads();
        int d = w*16 + l15;
        #pragma unroll
        for(int ks=0; ks<2; ks++){
            int tb = ks*4 + quad;
            s16x8 af = *(const s16x8*)&sQt[d*72 + tb*8];
            #pragma unroll
            for(int jt=0; jt<4; jt++){
                int e = jt*16 + l15;
                s16x8 bfv = *(const s16x8*)&sKt[e*72 + tb*8];
                acc[jt] = __builtin_amdgcn_mfma_f32_16x16x32_bf16(af, bfv, acc[jt], 0,0,0);
            }
        }
        __syncthreads();
    }

    float* S = Sp + (size_t)(kb*64 + head)*4096;
    #pragma unroll
    for(int jt=0; jt<4; jt++){
        int e = jt*16 + l15;
        #pragma unroll
        for(int r=0; r<4; r++){
            int d = w*16 + quad*4 + r;
            S[d*64 + e] = acc[jt][r];
        }
    }
}

// ---- sum 8 partials, softmax over e (scale 1/8); 256 blocks (4 d-strips/head) ----
__global__ void softmax64(const float* __restrict__ Sp, us* __restrict__ W){
    int head = blockIdx.x>>2, part = blockIdx.x&3;
    int t = threadIdx.x;           // 256
    int d = part*16 + (t>>4), e0 = (t&15)*4;
    float4 v = {0.f,0.f,0.f,0.f};
    for(int kb=0; kb<8; kb++){
        float4 f = *(const float4*)&Sp[(size_t)(kb*64 + head)*4096 + d*64 + e0];
        v.x+=f.x; v.y+=f.y; v.z+=f.z; v.w+=f.w;
    }
    v.x*=0.125f; v.y*=0.125f; v.z*=0.125f; v.w*=0.125f;
    float m = fmaxf(fmaxf(v.x,v.y), fmaxf(v.z,v.w));
    m = fmaxf(m, __shfl_xor(m, 1));
    m = fmaxf(m, __shfl_xor(m, 2));
    m = fmaxf(m, __shfl_xor(m, 4));
    m = fmaxf(m, __shfl_xor(m, 8));
    v.x=__expf(v.x-m); v.y=__expf(v.y-m); v.z=__expf(v.z-m); v.w=__expf(v.w-m);
    float s = v.x+v.y+v.z+v.w;
    s += __shfl_xor(s, 1);
    s += __shfl_xor(s, 2);
    s += __shfl_xor(s, 4);
    s += __shfl_xor(s, 8);
    float inv = 1.f/s;
    union{uint2 u; us h[4];} o;
    o.h[0]=f2bf(v.x*inv); o.h[1]=f2bf(v.y*inv); o.h[2]=f2bf(v.z*inv); o.h[3]=f2bf(v.w*inv);
    *(uint2*)&W[(size_t)head*4096 + d*64 + e0] = o.u;
}

// ---- M_{b,h}[nO,e] = sum_d wp[nO,h*64+d]*W[d,e]; 256 blocks (4 per head) ----
__launch_bounds__(256,2)
__global__ void fold(const us* __restrict__ Wsm, const us* __restrict__ wpbf,
                     us* __restrict__ Mcat){
    __shared__ us sWt[64*72];   // W^T: sWt[e][d]
    int t = threadIdx.x;
    int head = blockIdx.x>>2, part = blockIdx.x&3;
    int b = head>>3, h = head&7;
    int lane = t&63, w = t>>6, quad = lane>>4, l15 = lane&15;
    #pragma unroll
    for(int it=0; it<2; it++){
        int idx = it*2048 + t*8;
        int d = idx>>6, e0 = idx&63;
        union{uint4 v; us s[8];} q;
        q.v = *(const uint4*)&Wsm[(size_t)head*4096 + idx];
        #pragma unroll
        for(int j=0;j<8;j++) sWt[(e0+j)*72 + d] = q.s[j];
    }
    __syncthreads();
    #pragma unroll
    for(int i=0;i<2;i++){
        int nO = part*128 + w*32 + i*16 + l15;
        s16x8 af0 = *(const s16x8*)&wpbf[(size_t)nO*512 + h*64 + quad*8];
        s16x8 af1 = *(const s16x8*)&wpbf[(size_t)nO*512 + h*64 + 32 + quad*8];
        #pragma unroll
        for(int j=0;j<4;j++){
            s16x8 bf0 = *(const s16x8*)&sWt[(j*16+l15)*72 + quad*8];
            s16x8 bf1 = *(const s16x8*)&sWt[(j*16+l15)*72 + 32 + quad*8];
            f32x4 acc = (f32x4){0.f,0.f,0.f,0.f};
            acc = __builtin_amdgcn_mfma_f32_16x16x32_bf16(af0, bf0, acc, 0,0,0);
            acc = __builtin_amdgcn_mfma_f32_16x16x32_bf16(af1, bf1, acc, 0,0,0);
            #pragma unroll
            for(int r=0;r<4;r++){
                int row = part*128 + w*32 + i*16 + quad*4 + r;
                Mcat[((size_t)(b*512 + row))*512 + h*64 + j*16 + l15] = f2bf(acc[r]);
            }
        }
    }
}

// ---- out_b = Vgather_b @ Mcat_b^T + wp_b. BK=64 (one head per iter), swizzled. ----
__launch_bounds__(256,4)
__global__ void gemm_vout(const us* __restrict__ qkv, const us* __restrict__ Mcat,
                          const float* __restrict__ bias, float* __restrict__ out){
    __shared__ __attribute__((aligned(16))) us sA[128*64];
    __shared__ __attribute__((aligned(16))) us sB[128*64];
    int t = threadIdx.x;
    int id = blockIdx.x;                 // 1024
    int xcd = id & 7, s = id >> 3;
    int nt = s & 3, mt = xcd*32 + (s>>2);
    int b = mt>>5, mr = mt&31;
    int lane = t&63, wave = t>>6, quad = lane>>4, l15 = lane&15;
    int wm = wave>>1, wn = wave&1;

    int l8 = lane>>3;
    int sw = ((lane&7) ^ l8)*8;
    const us* Abase = qkv + ((size_t)(8*b)*512 + mr*16 + wave*4)*1536 + 1024 + l8*64 + sw;
    const us* Bbase = Mcat + ((size_t)(b*512 + nt*128 + wave*32 + l8))*512 + sw;
    us* sAw = &sA[(wave*32)*64];
    us* sBw = &sB[(wave*32)*64];

    f32x4 acc[4][4];
    #pragma unroll
    for(int i=0;i<4;i++)
        #pragma unroll
        for(int j=0;j<4;j++) acc[i][j] = (f32x4){0.f,0.f,0.f,0.f};

    for(int h=0; h<8; h++){
        const us* Ah = Abase + (size_t)h*512*1536;
        const us* Bh = Bbase + h*64;
        glds16(Ah,           sAw);
        glds16(Ah + 1536,    sAw + 8*64);
        glds16(Ah + 2*1536,  sAw + 16*64);
        glds16(Ah + 3*1536,  sAw + 24*64);
        glds16(Bh,           sBw);
        glds16(Bh + 8*512,   sBw + 8*64);
        glds16(Bh + 16*512,  sBw + 16*64);
        glds16(Bh + 24*512,  sBw + 24*64);
        __syncthreads();
        #pragma unroll
        for(int ks=0; ks<2; ks++){
            int kc = ks*4 + quad;
            s16x8 af[4], bfr[4];
            #pragma unroll
            for(int i=0;i<4;i++){
                int r = wm*64 + i*16 + l15;
                af[i] = *(const s16x8*)&sA[r*64 + ((kc ^ (r&7))<<3)];
            }
            #pragma unroll
            for(int j=0;j<4;j++){
                int r = wn*64 + j*16 + l15;
                bfr[j] = *(const s16x8*)&sB[r*64 + ((kc ^ (r&7))<<3)];
            }
            #pragma unroll
            for(int i=0;i<4;i++)
                #pragma unroll
                for(int j=0;j<4;j++)
                    acc[i][j] = __builtin_amdgcn_mfma_f32_16x16x32_bf16(af[i], bfr[j], acc[i][j], 0,0,0);
        }
        __syncthreads();
    }

    int row0 = b*4096 + mr*128 + wm*64;
    int col0 = nt*128 + wn*64;
    #pragma unroll
    for(int j=0;j<4;j++){
        int col = col0 + j*16 + l15;
        float bv = bias[col];
        #pragma unroll
        for(int i=0;i<4;i++){
            int rbase = row0 + i*16 + quad*4;
            #pragma unroll
            for(int r2=0;r2<4;r2++)
                out[(size_t)(rbase+r2)*512 + col] = acc[i][j][r2] + bv;
        }
    }
}

extern "C" void kernel_launch(void* const* d_in, const int* in_sizes, int n_in,
                              void* d_out, int out_size, void* d_ws, size_t ws_size,
                              hipStream_t stream){
    const float* x      = (const float*)d_in[0];
    const float* wqkv_w = (const float*)d_in[1];
    const float* wqkv_b = (const float*)d_in[2];
    const float* wp_w   = (const float*)d_in[3];
    const float* wp_b   = (const float*)d_in[4];

    char* ws = (char*)d_ws;
    us*    qkvbf  = (us*)(ws);                    // 96 MB
    us*    xbf    = (us*)(ws + 100663296);        // 32 MB
    float* Spart  = (float*)(ws + 134217728);     // 8 MB
    us*    Wsm    = (us*)(ws + 142606336);        // 0.5 MB
    us*    Mcat   = (us*)(ws + 143130624);        // 4 MB
    us*    wqkvbf = (us*)(ws + 147324928);        // 1.5 MB
    us*    wpbf   = (us*)(ws + 148897792);        // 0.5 MB

    cast_all<<<17408,256,0,stream>>>(x, wqkv_w, wp_w, xbf, wqkvbf, wpbf);

    gemm_qkv<<<3072,256,0,stream>>>(xbf, wqkvbf, wqkv_b, qkvbf);

    attn_scores_mfma<<<dim3(8,64),256,0,stream>>>(qkvbf, Spart);
    softmax64<<<256,256,0,stream>>>(Spart, Wsm);
    fold<<<256,256,0,stream>>>(Wsm, wpbf, Mcat);

    gemm_vout<<<1024,256,0,stream>>>(qkvbf, Mcat, wp_b, (float*)d_out);
}